// Round 23
// baseline (73.863 us; speedup 1.0000x reference)
//
#include <hip/hip_runtime.h>

#define LN2 0.6931471805599453f

constexpr int T = 512, N = 32, C = 4000, S = 64;
constexpr int TN   = T * N;
constexpr int ROWF = 68;          // pp row stride (272B; 17 lanes x 16B DMA)
constexpr int CT   = 16;          // chunk rows (all paths)
constexpr int NCF  = 10;          // E: forward chunks (t in [0,160))
constexpr int NCBT = 6;           // E: backward tail chunks (rows 255..160)
constexpr int NCBP = 16;          // B: hidden backward chunks (rows 511..256)
constexpr int NCG  = 32;          // generic-path chunks (full T)
constexpr int HROWS = 8192;       // rows per k1 half (256 t x 32 n)

// ---------------- DPP helpers ------------------------------------------------
__device__ __forceinline__ float dpp_shr1_zero(float x) {   // lane-1; lane0<-0
    int r = __builtin_amdgcn_update_dpp(0, __float_as_int(x),
                                        0x138 /*wave_shr:1*/, 0xf, 0xf, false);
    return __int_as_float(r);
}
__device__ __forceinline__ float dpp_shl1_zero(float x) {   // lane+1; lane63<-0
    int r = __builtin_amdgcn_update_dpp(0, __float_as_int(x),
                                        0x130 /*wave_shl:1*/, 0xf, 0xf, false);
    return __int_as_float(r);
}
template <int CTRL>
__device__ __forceinline__ float dpp_max_step(float x) {
    int t = __builtin_amdgcn_update_dpp(__float_as_int(x), __float_as_int(x),
                                        CTRL, 0xf, 0xf, false);
    return fmaxf(x, __int_as_float(t));
}
__device__ __forceinline__ float wave_max_bcast(float x) {
    x = dpp_max_step<0xB1>(x);  x = dpp_max_step<0x4E>(x);
    x = dpp_max_step<0x141>(x); x = dpp_max_step<0x140>(x);
    x = dpp_max_step<0x142>(x); x = dpp_max_step<0x143>(x);
    return __int_as_float(__builtin_amdgcn_readlane(__float_as_int(x), 63));
}

// ---------------- softmax for one (t,n) row (R11-proven) ---------------------
__device__ __forceinline__ void softmax_row(
    const float* __restrict__ x, const int* __restrict__ labels,
    float* __restrict__ pp, float* __restrict__ ee, int row, int lane)
{
    const float*  rp  = x + (size_t)row * C;
    const float4* rp4 = reinterpret_cast<const float4*>(rp);

    float m = -INFINITY, s = 0.f;
    #pragma unroll
    for (int k = 0; k < 15; ++k) {                 // 960 of 1000 float4s
        float4 v = rp4[lane + 64 * k];
        float mv = fmaxf(fmaxf(v.x, v.y), fmaxf(v.z, v.w));
        float s4 = __expf(v.x - mv) + __expf(v.y - mv) +
                   __expf(v.z - mv) + __expf(v.w - mv);
        float nm = fmaxf(m, mv);
        s = s * __expf(m - nm) + s4 * __expf(mv - nm);
        m = nm;
    }
    if (lane < 40) {                               // tail 40 float4s
        float4 v = rp4[960 + lane];
        float mv = fmaxf(fmaxf(v.x, v.y), fmaxf(v.z, v.w));
        float s4 = __expf(v.x - mv) + __expf(v.y - mv) +
                   __expf(v.z - mv) + __expf(v.w - mv);
        float nm = fmaxf(m, mv);
        s = s * __expf(m - nm) + s4 * __expf(mv - nm);
        m = nm;
    }
    for (int off = 32; off; off >>= 1) {
        float om = __shfl_xor(m, off), os = __shfl_xor(s, off);
        float nm = fmaxf(m, om);
        s = s * __expf(m - nm) + os * __expf(om - nm);
        m = nm;
    }
    float logZ = m + __logf(s);

    int t = row >> 5, n = row & 31;
    int c  = labels[n * S + lane];
    float zb = rp[0];
    float zl = rp[c];

    float wm = zl;
    for (int off = 32; off; off >>= 1) wm = fmaxf(wm, __shfl_xor(wm, off));
    wm = fmaxf(wm, zb);
    float pm = __expf(wm - logZ);
    int e = (int)(__float_as_uint(pm) >> 23) - 127;

    float* outp = pp + ((size_t)n * T + t) * ROWF;
    outp[1 + lane] = ldexpf(__expf(zl - logZ), -e);
    if (lane == 0) {
        outp[0] = ldexpf(__expf(zb - logZ), -e);
        ee[n * T + t] = (float)e;
    }
}

// ---- backward composed pair (R19/R20/R21-proven): rows (D+1) then (D) ------
#define CPAIR_BODY(LDSPTR, B, D) do {                                         \
    const float* Ru_ = LDSPTR(B, D);                                          \
    const float* Rv_ = LDSPTR(B, (D) + 1);                                    \
    float ub_ = Ru_[0], ul_ = Ru_[1 + lane];                                  \
    float vb_ = Rv_[0], vl_ = Rv_[1 + lane];                                  \
    float ulp_ = dpp_shl1_zero(ul_);                                          \
    float vlp_ = dpp_shl1_zero(vl_);                                          \
    float vlpp_ = dpp_shl1_zero(vlp_);                                        \
    float A2_  = ub_ * vb_;                                                   \
    float uv_  = ul_ * vl_;                                                   \
    float c00_ = vl_ * (ub_ + ul_);                                           \
    float c01_ = ul_ * vb_;                                                   \
    float c02_ = (ul_ * skD) * vlp_;                                          \
    float d01_ = (ul_ + ub_) * vb_;                                           \
    float d02_ = vlp_ * fmaf(skD, ul_ + ulp_, ub_);                           \
    float d03_ = (skD * vb_) * ulp_;                                          \
    float d04_ = ((skD * skD2) * ulp_) * vlpp_;                               \
    float g0n1s_ = dpp_shl1_zero(g0);                                         \
    float g0n1_ = (lane == 63) ? gX : g0n1s_;                                 \
    float g1n1_ = dpp_shl1_zero(g1);                                          \
    float g0n2_ = dpp_shl1_zero(g0n1_);          /* lane62 <- gX */           \
    float g1n2_ = dpp_shl1_zero(g1n1_);                                       \
    float n0_ = fmaf(g0, A2_, g1 * c00_) + fmaf(g0n1_, c01_, g1n1_ * c02_);   \
    float n1_ = fmaf(g1, uv_, g0n1_ * d01_) +                                 \
                fmaf(g1n1_, d02_, fmaf(g0n2_, d03_, g1n2_ * d04_));           \
    float nX_ = A2_ * gX;                                                     \
    g0 = n0_; g1 = n1_; gX = nX_;                                             \
} while (0)

// 8 rows (4 CPAIRs) + lag-2 off-chain renorm anchor 90 (R18/R20/R21-proven)
#define BWINC_BODY(LDSPTR, B, D0) do {                                        \
    g0 = ldexpf(g0, kB); g1 = ldexpf(g1, kB); gX = ldexpf(gX, kB);            \
    SHb += kB;                                                                \
    float gnow_ = fmaxf(fmaxf(g0, g1), gX);                                   \
    CPAIR_BODY(LDSPTR, B, (D0) + 6);                                          \
    gsb = dpp_max_step<0xB1>(gsb);  gsb = dpp_max_step<0x4E>(gsb);            \
    CPAIR_BODY(LDSPTR, B, (D0) + 4);                                          \
    gsb = dpp_max_step<0x141>(gsb); gsb = dpp_max_step<0x140>(gsb);           \
    CPAIR_BODY(LDSPTR, B, (D0) + 2);                                          \
    gsb = dpp_max_step<0x142>(gsb); gsb = dpp_max_step<0x143>(gsb);           \
    CPAIR_BODY(LDSPTR, B, (D0));                                              \
    {   unsigned b_ = (unsigned)__builtin_amdgcn_readlane(__float_as_int(gsb), 63); \
        int e_ = (int)(b_ >> 23) - 127;                                       \
        kB = (b_ == 0u) ? 0 : (90 - e_ - kB);                                 \
    }                                                                         \
    gsb = gnow_;                                                              \
} while (0)

// ---------------- phase kernel: k1 half + (optional) hidden 256-row bwd -----
// Blocks 0..7 (dispatch first): backward gamma rows 511..256, 4 n each.
// In phase A (dobwd==0) block 0 zeroes out[0] (replaces hipMemsetAsync).
// Blocks 8..2055: softmax rows [hrow0, hrow0+8192).
__global__ __launch_bounds__(256) void k_phase(
    const float* __restrict__ x, const int* __restrict__ labels,
    float* __restrict__ pp, float* __restrict__ ee, float* __restrict__ gst,
    const int* __restrict__ in_len, const int* __restrict__ lab_len,
    float* __restrict__ out, int hrow0, int dobwd)
{
    __shared__ __align__(16) float ldsB[4][2][CT][ROWF];   // 34.8 KB
    const int wid = threadIdx.x >> 6, lane = threadIdx.x & 63;

    if (blockIdx.x >= 8) {
        softmax_row(x, labels, pp, ee,
                    hrow0 + ((int)blockIdx.x - 8) * 4 + wid, lane);
        return;
    }
    if (!dobwd) {                                // phase A: zero the output
        if (blockIdx.x == 0 && threadIdx.x == 0) out[0] = 0.f;
        return;
    }
    const int n = blockIdx.x * 4 + wid;
    const int Tin = in_len[n], Sl = lab_len[n];
    if (Tin != T) return;                        // generic n handled in k_final
    const float* bp = pp + (size_t)n * T * ROWF;

    const int li = labels[n * S + lane];
    const float skf = (lane > 0 && li != 0 &&
                       li != labels[n * S + lane - 1]) ? 1.f : 0.f;
    const float skD  = dpp_shl1_zero(skf);       // allow_skip into 2i+3
    const float skD2 = dpp_shl1_zero(skD);       // allow_skip into 2i+5

    // unit init at t = 511
    float g0 = (lane == Sl) ? 1.f : 0.f;                 // l = 2*Sl (Sl<=63)
    float g1 = (Sl > 0 && lane == Sl - 1) ? 1.f : 0.f;   // l = 2*Sl-1
    float gX = (Sl >= S && lane == 63) ? 1.f : 0.f;      // l = 128 (Sl==64)
    int SHb = 0, kB = 0;
    float gsb = fmaxf(fmaxf(g0, g1), gX);

    asm volatile("s_waitcnt vmcnt(0)" ::: "memory");
    __builtin_amdgcn_sched_barrier(0);

#define LDSP(B, D) (&ldsB[wid][B][D][0])
#define ISSUEB(cc) do {                                                       \
    const float* cp_ = bp + (size_t)(496 - 16 * (cc)) * ROWF;                 \
    if (lane < 17) {                                                          \
        _Pragma("unroll")                                                     \
        for (int d_ = 0; d_ < CT; ++d_)                                       \
            __builtin_amdgcn_global_load_lds(cp_ + (size_t)d_ * ROWF + lane * 4, \
                                             &ldsB[wid][(cc) & 1][d_][0], 16, 0, 0); \
    } } while (0)

    ISSUEB(0); ISSUEB(1);
    for (int c = 0; c < NCBP; ++c) {             // rows 511..256 descending
        if (c < NCBP - 1) { asm volatile("s_waitcnt vmcnt(16)" ::: "memory"); }
        else              { asm volatile("s_waitcnt vmcnt(0)"  ::: "memory"); }
        __builtin_amdgcn_sched_barrier(0);
        int buf = c & 1;
        BWINC_BODY(LDSP, buf, 8);                // rows 15..8 of chunk
        BWINC_BODY(LDSP, buf, 0);                // rows 7..0
        if (c + 2 < NCBP) {
            __builtin_amdgcn_sched_barrier(0);
            ISSUEB(c + 2);
        }
    }

    // publish gamma_255 state (pending kB intentionally dropped; SHb = applied)
    float* st = gst + n * 136;
    float2 gv; gv.x = g0; gv.y = g1;
    *reinterpret_cast<float2*>(&st[2 * lane]) = gv;
    if (lane == 63) { st[128] = gX; st[129] = (float)SHb; }
#undef ISSUEB
#undef LDSP
}

// ---------------- final kernel: fwd(0..159) || bwd(255..160) + join@159 -----
__global__ __launch_bounds__(128) void k_final(
    const float* __restrict__ pp, const float* __restrict__ ee,
    float* __restrict__ gst, const int* __restrict__ labels,
    const int* __restrict__ in_len, const int* __restrict__ lab_len,
    float* __restrict__ out)
{
    __shared__ __align__(16) float ldsF[2][CT][ROWF];
    __shared__ __align__(16) float ldsT[2][CT][ROWF];
    __shared__ float gj[132];
    const int n = blockIdx.x;
    const int wid = threadIdx.x >> 6, lane = threadIdx.x & 63;
    const int Tin = in_len[n], Sl = lab_len[n];
    const float* bp = pp + (size_t)n * T * ROWF;
    const bool hot = (Tin == T);

    const int li   = labels[n * S + lane];
    const int lim1 = lane ? labels[n * S + lane - 1] : -1;
    const float skf  = (lane > 0 && li != 0 && li != lim1) ? 1.f : 0.f;
    const float skUf = dpp_shr1_zero(skf);
    const float skk  = skf * skUf;
    const float skD  = dpp_shl1_zero(skf);
    const float skD2 = dpp_shl1_zero(skD);

    float a0 = 0.f, a1 = 0.f, aX = 0.f;
    int SH = 0;

#define ISSUE_F(cc) do {                                                      \
    const float* cp_ = bp + (size_t)(cc) * CT * ROWF;                         \
    if (lane < 17) {                                                          \
        _Pragma("unroll")                                                     \
        for (int d_ = 0; d_ < CT; ++d_)                                       \
            __builtin_amdgcn_global_load_lds(cp_ + (size_t)d_ * ROWF + lane * 4, \
                                             &ldsF[(cc) & 1][d_][0], 16, 0, 0); \
    } } while (0)
#define ISSUE_T(cc) do {                                                      \
    const float* cp_ = bp + (size_t)(240 - 16 * (cc)) * ROWF;                 \
    if (lane < 17) {                                                          \
        _Pragma("unroll")                                                     \
        for (int d_ = 0; d_ < CT; ++d_)                                       \
            __builtin_amdgcn_global_load_lds(cp_ + (size_t)d_ * ROWF + lane * 4, \
                                             &ldsT[(cc) & 1][d_][0], 16, 0, 0); \
    } } while (0)

// ---- forward pair step (R11 verbatim) ----
#define PAIRS(B, D) do {                                                      \
    const float* R0_ = &ldsF[B][D][0];                                        \
    const float* R1_ = &ldsF[B][(D) + 1][0];                                  \
    float cb1 = R0_[0], cl1 = R0_[1 + lane];                                  \
    float cb2 = R1_[0], cl2 = R1_[1 + lane];                                  \
    float clU = dpp_shr1_zero(cl1);                                           \
    float W   = clU * cl2;                                                    \
    float A   = cb1 * cb2;                                                    \
    float B_  = clU * cb2;                                                    \
    float Cc  = A + B_;                                                       \
    float D_  = skUf * B_;                                                    \
    float s1  = cb1 + cl1;                                                    \
    float E   = s1 * cl2;                                                     \
    float F   = cl1 * cl2;                                                    \
    float G   = skf * W;                                                      \
    float H   = fmaf(skf, F + W, cb1 * cl2);                                  \
    float I   = skk * W;                                                      \
    float Y0  = cl1 * cb2;                                                    \
    float Y1  = s1 * cb2;                                                     \
    float Y2  = skf * Y0;                                                     \
    float p1  = dpp_shr1_zero(a1);                                            \
    float p0  = dpp_shr1_zero(a0);                                            \
    float p2  = dpp_shr1_zero(p1);                                            \
    float n0  = fmaf(p0, B_, a0 * A) + fmaf(p2, D_, p1 * Cc);                 \
    float n1  = fmaf(a1, F, a0 * E) + fmaf(p2, I, fmaf(p1, H, p0 * G));       \
    float nX  = fmaf(a1, Y1, aX * A) + fmaf(p1, Y2, a0 * Y0);                 \
    a0 = n0; a1 = n1; aX = nX;                                                \
} while (0)

#define WINDOW4(B, D0) do {                                                   \
    a0 = ldexpf(a0, kA); a1 = ldexpf(a1, kA); aX = ldexpf(aX, kA);            \
    SH += kA;                                                                 \
    float gnow_ = fmaxf(fmaxf(a0, a1), aX);                                   \
    PAIRS(B, D0);                                                             \
    gs = dpp_max_step<0xB1>(gs);  gs = dpp_max_step<0x4E>(gs);                \
    PAIRS(B, (D0) + 2);                                                       \
    gs = dpp_max_step<0x141>(gs); gs = dpp_max_step<0x140>(gs);               \
    PAIRS(B, (D0) + 4);                                                       \
    gs = dpp_max_step<0x142>(gs); gs = dpp_max_step<0x143>(gs);               \
    PAIRS(B, (D0) + 6);                                                       \
    {   unsigned b_ = (unsigned)__builtin_amdgcn_readlane(__float_as_int(gs), 63); \
        int e_ = (int)(b_ >> 23) - 127;                                       \
        kA = (b_ == 0u) ? 0 : (105 - e_ - kA);                                \
    }                                                                         \
    gs = gnow_;                                                               \
} while (0)

#define LDST(B, D) (&ldsT[B][D][0])

    asm volatile("s_waitcnt vmcnt(0)" ::: "memory");
    __builtin_amdgcn_sched_barrier(0);

    if (wid == 0) {
        if (hot) {
            // forward t = 0..159 (10 chunks)
            int kA = 0; float gs = 0.f;
            ISSUE_F(0); ISSUE_F(1);
            asm volatile("s_waitcnt vmcnt(16)" ::: "memory");
            __builtin_amdgcn_sched_barrier(0);
            a0 = (lane == 0) ? ldsF[0][0][0] : 0.f;
            a1 = (lane == 0 && Sl > 0) ? ldsF[0][0][1] : 0.f;
            {   // t = 1 single step
                float cb = ldsF[0][1][0], cl = ldsF[0][1][1 + lane];
                float p1 = dpp_shr1_zero(a1);
                float n0 = (a0 + p1) * cb;
                float n1 = fmaf(skf, p1, a0 + a1) * cl;
                float nX = (aX + a1) * cb;
                a0 = n0; a1 = n1; aX = nX;
            }
            PAIRS(0, 2); PAIRS(0, 4); PAIRS(0, 6);       // t = 2..7
            {   float g = wave_max_bcast(fmaxf(fmaxf(a0, a1), aX));
                unsigned b = __float_as_uint(g);
                int k0 = (b == 0u) ? 0 : (105 - ((int)(b >> 23) - 127));
                a0 = ldexpf(a0, k0); a1 = ldexpf(a1, k0); aX = ldexpf(aX, k0);
                SH += k0; kA = 0;
                gs = fmaxf(fmaxf(a0, a1), aX);
            }
            WINDOW4(0, 8);                               // t = 8..15
            __builtin_amdgcn_sched_barrier(0);
            ISSUE_F(2);
            for (int c = 1; c < NCF; ++c) {
                if (c < NCF - 1) { asm volatile("s_waitcnt vmcnt(16)" ::: "memory"); }
                else             { asm volatile("s_waitcnt vmcnt(0)"  ::: "memory"); }
                __builtin_amdgcn_sched_barrier(0);
                int buf = c & 1;
                WINDOW4(buf, 0);
                WINDOW4(buf, 8);
                if (c + 2 < NCF) {
                    __builtin_amdgcn_sched_barrier(0);
                    ISSUE_F(c + 2);
                }
            }
        } else {
            // generic fallback: full T per-step (R11-proven structure)
#define GSTEP(cc, dd) do {                                                    \
    float cb_ = ldsF[(cc) & 1][dd][0];                                        \
    float cl_ = ldsF[(cc) & 1][dd][1 + lane];                                 \
    float p1_ = dpp_shr1_zero(a1);                                            \
    float na0_ = (a0 + p1_) * cb_;                                            \
    float na1_ = fmaf(skf, p1_, a0 + a1) * cl_;                               \
    float naX_ = (aX + a1) * cb_;                                             \
    int t_ = (cc) * CT + (dd);                                                \
    bool act_ = (unsigned)(t_ - 1) < (unsigned)(Tin - 1);                     \
    a0 = act_ ? na0_ : a0;                                                    \
    a1 = act_ ? na1_ : a1;                                                    \
    aX = act_ ? naX_ : aX;                                                    \
    if (((dd) & 3) == 3) {                                                    \
        float g_ = wave_max_bcast(fmaxf(a0, fmaxf(a1, aX)));                  \
        unsigned b_ = __float_as_uint(g_);                                    \
        int k_ = (b_ == 0u) ? 0 : (100 - ((int)(b_ >> 23) - 127));            \
        a0 = ldexpf(a0, k_); a1 = ldexpf(a1, k_); aX = ldexpf(aX, k_);        \
        SH += k_;                                                             \
    }                                                                         \
} while (0)
            ISSUE_F(0); ISSUE_F(1);
            asm volatile("s_waitcnt vmcnt(16)" ::: "memory");
            __builtin_amdgcn_sched_barrier(0);
            a0 = (lane == 0) ? ldsF[0][0][0] : 0.f;
            a1 = (lane == 0 && Sl > 0) ? ldsF[0][0][1] : 0.f;
            #pragma unroll
            for (int d = 1; d < CT; ++d) GSTEP(0, d);
            __builtin_amdgcn_sched_barrier(0);
            ISSUE_F(2);
            for (int c = 1; c < NCG; ++c) {
                if (c < NCG - 1) { asm volatile("s_waitcnt vmcnt(16)" ::: "memory"); }
                else             { asm volatile("s_waitcnt vmcnt(0)"  ::: "memory"); }
                __builtin_amdgcn_sched_barrier(0);
                #pragma unroll
                for (int d = 0; d < CT; ++d) GSTEP(c, d);
                if (c + 2 < NCG) {
                    __builtin_amdgcn_sched_barrier(0);
                    ISSUE_F(c + 2);
                }
            }
#undef GSTEP
        }
    } else if (hot) {
        // backward tail: rows 255..160 (6 chunks, CPAIR), then publish gamma_159
        float* st = gst + n * 136;
        float2 g = *reinterpret_cast<const float2*>(&st[2 * lane]);
        float g0 = g.x, g1 = g.y;
        float gX = (lane == 63) ? st[128] : 0.f;
        int SHb = (int)st[129], kB = 0;
        float gsb = fmaxf(fmaxf(g0, g1), gX);

        ISSUE_T(0); ISSUE_T(1);
        for (int c = 0; c < NCBT; ++c) {
            if (c < NCBT - 1) { asm volatile("s_waitcnt vmcnt(16)" ::: "memory"); }
            else              { asm volatile("s_waitcnt vmcnt(0)"  ::: "memory"); }
            __builtin_amdgcn_sched_barrier(0);
            int buf = c & 1;
            BWINC_BODY(LDST, buf, 8);                    // rows 15..8
            BWINC_BODY(LDST, buf, 0);                    // rows 7..0
            if (c + 2 < NCBT) {
                __builtin_amdgcn_sched_barrier(0);
                ISSUE_T(c + 2);
            }
        }
        gj[2 * lane]     = g0;                           // UNSHIFTED (fp64 join)
        gj[2 * lane + 1] = g1;
        if (lane == 63) { gj[128] = gX; gj[130] = (float)SHb; }
    }

    __syncthreads();
    if (wid != 0) return;

    // ---------------- epilogue (wave 0) ----------------
    float se = 0.f;
    #pragma unroll
    for (int j = 0; j < 8; ++j) {
        int idx = lane + 64 * j;
        float ev = ee[n * T + idx];
        se += (idx < Tin) ? ev : 0.f;
    }
    for (int off = 32; off; off >>= 1) se += __shfl_xor(se, off);

    if (hot) {
        // P = sum_l alpha_159[l] * gamma_159[l]  (fp64)
        double term = (double)a0 * (double)gj[2 * lane]
                    + (double)a1 * (double)gj[2 * lane + 1];
        if (lane == 63) term += (double)aX * (double)gj[128];
        for (int off = 32; off; off >>= 1) term += __shfl_xor(term, off);
        if (lane == 0) {
            double SHb = (double)gj[130];
            double ll2 = log2(term) - (double)SH - SHb + (double)se;
            float loss = (float)(-ll2 * (double)LN2);
            if (!(loss < 5e29f)) loss = 0.f;             // zero_infinity (+NaN)
            atomicAdd(out, loss);
        }
    } else {
        float a_last = (Sl >= S) ? __shfl(aX, 63) : __shfl(a0, Sl);
        float a_prev_raw = __shfl(a1, (Sl > 0) ? (Sl - 1) : 0);
        float a_prev = (Sl > 0) ? a_prev_raw : 0.f;
        if (lane == 0) {
            float sum  = a_last + a_prev;
            float ll2  = log2f(sum) - (float)SH + se;
            float loss = -ll2 * LN2;
            if (!(loss < 5e29f)) loss = 0.f;
            atomicAdd(out, loss);
        }
    }
#undef LDST
#undef WINDOW4
#undef PAIRS
#undef ISSUE_F
#undef ISSUE_T
}

extern "C" void kernel_launch(void* const* d_in, const int* in_sizes, int n_in,
                              void* d_out, int out_size, void* d_ws, size_t ws_size,
                              hipStream_t stream) {
    const float* x       = (const float*)d_in[0];
    const int*   labels  = (const int*)d_in[1];
    const int*   in_len  = (const int*)d_in[2];
    const int*   lab_len = (const int*)d_in[3];
    float* out  = (float*)d_out;
    float* pp   = (float*)d_ws;                          // TN*ROWF floats
    float* ee   = pp + (size_t)TN * ROWF + 256;          // TN floats
    float* gst  = ee + TN + 32;                          // N*136 floats

    const int NB = 8 + HROWS / 4;                        // 2056 blocks
    // A: k1 for t in [256,512); block 0 zeroes out[0] (replaces memset)
    k_phase<<<NB, 256, 0, stream>>>(x, labels, pp, ee, gst, in_len, lab_len,
                                    out, HROWS, 0);
    // B: k1 for t in [0,256) + hidden bwd rows 511..256 (CPAIR)
    k_phase<<<NB, 256, 0, stream>>>(x, labels, pp, ee, gst, in_len, lab_len,
                                    out, 0, 1);
    // E: fwd(0..159) || bwd(255..160) + join@159 (fp64) + atomic sum
    k_final<<<N, 128, 0, stream>>>(pp, ee, gst, labels, in_len, lab_len, out);
}

// Round 24
// 72.704 us; speedup vs baseline: 1.0159x; 1.0159x over previous
//
#include <hip/hip_runtime.h>

#define LN2 0.6931471805599453f

constexpr int T = 512, N = 32, C = 4000, S = 64;
constexpr int TN   = T * N;
constexpr int ROWF = 68;          // pp row stride (272B; 17 lanes x 16B DMA)
constexpr int CT   = 16;          // chunk rows (all paths)
constexpr int NCF  = 8;           // E: forward chunks (t in [0,128))
constexpr int NCBT = 8;           // E: backward tail chunks (rows 255..128)
constexpr int NCBP = 16;          // B: hidden backward chunks (rows 511..256)
constexpr int NCG  = 32;          // generic-path chunks (full T)
constexpr int HROWS = 8192;       // rows per k1 half (256 t x 32 n)

// ---------------- DPP helpers ------------------------------------------------
__device__ __forceinline__ float dpp_shr1_zero(float x) {   // lane-1; lane0<-0
    int r = __builtin_amdgcn_update_dpp(0, __float_as_int(x),
                                        0x138 /*wave_shr:1*/, 0xf, 0xf, false);
    return __int_as_float(r);
}
__device__ __forceinline__ float dpp_shl1_zero(float x) {   // lane+1; lane63<-0
    int r = __builtin_amdgcn_update_dpp(0, __float_as_int(x),
                                        0x130 /*wave_shl:1*/, 0xf, 0xf, false);
    return __int_as_float(r);
}
template <int CTRL>
__device__ __forceinline__ float dpp_max_step(float x) {
    int t = __builtin_amdgcn_update_dpp(__float_as_int(x), __float_as_int(x),
                                        CTRL, 0xf, 0xf, false);
    return fmaxf(x, __int_as_float(t));
}
__device__ __forceinline__ float wave_max_bcast(float x) {
    x = dpp_max_step<0xB1>(x);  x = dpp_max_step<0x4E>(x);
    x = dpp_max_step<0x141>(x); x = dpp_max_step<0x140>(x);
    x = dpp_max_step<0x142>(x); x = dpp_max_step<0x143>(x);
    return __int_as_float(__builtin_amdgcn_readlane(__float_as_int(x), 63));
}

// ---------------- softmax for one (t,n) row (R11-proven) ---------------------
__device__ __forceinline__ void softmax_row(
    const float* __restrict__ x, const int* __restrict__ labels,
    float* __restrict__ pp, float* __restrict__ ee, int row, int lane)
{
    const float*  rp  = x + (size_t)row * C;
    const float4* rp4 = reinterpret_cast<const float4*>(rp);

    float m = -INFINITY, s = 0.f;
    #pragma unroll
    for (int k = 0; k < 15; ++k) {                 // 960 of 1000 float4s
        float4 v = rp4[lane + 64 * k];
        float mv = fmaxf(fmaxf(v.x, v.y), fmaxf(v.z, v.w));
        float s4 = __expf(v.x - mv) + __expf(v.y - mv) +
                   __expf(v.z - mv) + __expf(v.w - mv);
        float nm = fmaxf(m, mv);
        s = s * __expf(m - nm) + s4 * __expf(mv - nm);
        m = nm;
    }
    if (lane < 40) {                               // tail 40 float4s
        float4 v = rp4[960 + lane];
        float mv = fmaxf(fmaxf(v.x, v.y), fmaxf(v.z, v.w));
        float s4 = __expf(v.x - mv) + __expf(v.y - mv) +
                   __expf(v.z - mv) + __expf(v.w - mv);
        float nm = fmaxf(m, mv);
        s = s * __expf(m - nm) + s4 * __expf(mv - nm);
        m = nm;
    }
    for (int off = 32; off; off >>= 1) {
        float om = __shfl_xor(m, off), os = __shfl_xor(s, off);
        float nm = fmaxf(m, om);
        s = s * __expf(m - nm) + os * __expf(om - nm);
        m = nm;
    }
    float logZ = m + __logf(s);

    int t = row >> 5, n = row & 31;
    int c  = labels[n * S + lane];
    float zb = rp[0];
    float zl = rp[c];

    float wm = zl;
    for (int off = 32; off; off >>= 1) wm = fmaxf(wm, __shfl_xor(wm, off));
    wm = fmaxf(wm, zb);
    float pm = __expf(wm - logZ);
    int e = (int)(__float_as_uint(pm) >> 23) - 127;

    float* outp = pp + ((size_t)n * T + t) * ROWF;
    outp[1 + lane] = ldexpf(__expf(zl - logZ), -e);
    if (lane == 0) {
        outp[0] = ldexpf(__expf(zb - logZ), -e);
        ee[n * T + t] = (float)e;
    }
}

// ---- backward composed pair (R19/R20/R21-proven): rows (D+1) then (D) ------
#define CPAIR_BODY(LDSPTR, B, D) do {                                         \
    const float* Ru_ = LDSPTR(B, D);                                          \
    const float* Rv_ = LDSPTR(B, (D) + 1);                                    \
    float ub_ = Ru_[0], ul_ = Ru_[1 + lane];                                  \
    float vb_ = Rv_[0], vl_ = Rv_[1 + lane];                                  \
    float ulp_ = dpp_shl1_zero(ul_);                                          \
    float vlp_ = dpp_shl1_zero(vl_);                                          \
    float vlpp_ = dpp_shl1_zero(vlp_);                                        \
    float A2_  = ub_ * vb_;                                                   \
    float uv_  = ul_ * vl_;                                                   \
    float c00_ = vl_ * (ub_ + ul_);                                           \
    float c01_ = ul_ * vb_;                                                   \
    float c02_ = (ul_ * skD) * vlp_;                                          \
    float d01_ = (ul_ + ub_) * vb_;                                           \
    float d02_ = vlp_ * fmaf(skD, ul_ + ulp_, ub_);                           \
    float d03_ = (skD * vb_) * ulp_;                                          \
    float d04_ = ((skD * skD2) * ulp_) * vlpp_;                               \
    float g0n1s_ = dpp_shl1_zero(g0);                                         \
    float g0n1_ = (lane == 63) ? gX : g0n1s_;                                 \
    float g1n1_ = dpp_shl1_zero(g1);                                          \
    float g0n2_ = dpp_shl1_zero(g0n1_);          /* lane62 <- gX */           \
    float g1n2_ = dpp_shl1_zero(g1n1_);                                       \
    float n0_ = fmaf(g0, A2_, g1 * c00_) + fmaf(g0n1_, c01_, g1n1_ * c02_);   \
    float n1_ = fmaf(g1, uv_, g0n1_ * d01_) +                                 \
                fmaf(g1n1_, d02_, fmaf(g0n2_, d03_, g1n2_ * d04_));           \
    float nX_ = A2_ * gX;                                                     \
    g0 = n0_; g1 = n1_; gX = nX_;                                             \
} while (0)

// 8 rows (4 CPAIRs) + lag-2 off-chain renorm anchor 90 (R18/R20/R21-proven)
#define BWINC_BODY(LDSPTR, B, D0) do {                                        \
    g0 = ldexpf(g0, kB); g1 = ldexpf(g1, kB); gX = ldexpf(gX, kB);            \
    SHb += kB;                                                                \
    float gnow_ = fmaxf(fmaxf(g0, g1), gX);                                   \
    CPAIR_BODY(LDSPTR, B, (D0) + 6);                                          \
    gsb = dpp_max_step<0xB1>(gsb);  gsb = dpp_max_step<0x4E>(gsb);            \
    CPAIR_BODY(LDSPTR, B, (D0) + 4);                                          \
    gsb = dpp_max_step<0x141>(gsb); gsb = dpp_max_step<0x140>(gsb);           \
    CPAIR_BODY(LDSPTR, B, (D0) + 2);                                          \
    gsb = dpp_max_step<0x142>(gsb); gsb = dpp_max_step<0x143>(gsb);           \
    CPAIR_BODY(LDSPTR, B, (D0));                                              \
    {   unsigned b_ = (unsigned)__builtin_amdgcn_readlane(__float_as_int(gsb), 63); \
        int e_ = (int)(b_ >> 23) - 127;                                       \
        kB = (b_ == 0u) ? 0 : (90 - e_ - kB);                                 \
    }                                                                         \
    gsb = gnow_;                                                              \
} while (0)

// ---------------- phase kernel: k1 half + (optional) hidden 256-row bwd -----
// Blocks 0..7 (dispatch first): backward gamma rows 511..256, 4 n each.
// In phase A (dobwd==0) block 0 zeroes out[0] (replaces hipMemsetAsync).
// Blocks 8..2055: softmax rows [hrow0, hrow0+8192).
__global__ __launch_bounds__(256) void k_phase(
    const float* __restrict__ x, const int* __restrict__ labels,
    float* __restrict__ pp, float* __restrict__ ee, float* __restrict__ gst,
    const int* __restrict__ in_len, const int* __restrict__ lab_len,
    float* __restrict__ out, int hrow0, int dobwd)
{
    __shared__ __align__(16) float ldsB[4][2][CT][ROWF];   // 34.8 KB
    const int wid = threadIdx.x >> 6, lane = threadIdx.x & 63;

    if (blockIdx.x >= 8) {
        softmax_row(x, labels, pp, ee,
                    hrow0 + ((int)blockIdx.x - 8) * 4 + wid, lane);
        return;
    }
    if (!dobwd) {                                // phase A: zero the output
        if (blockIdx.x == 0 && threadIdx.x == 0) out[0] = 0.f;
        return;
    }
    const int n = blockIdx.x * 4 + wid;
    const int Tin = in_len[n], Sl = lab_len[n];
    if (Tin != T) return;                        // generic n handled in k_final
    const float* bp = pp + (size_t)n * T * ROWF;

    const int li = labels[n * S + lane];
    const float skf = (lane > 0 && li != 0 &&
                       li != labels[n * S + lane - 1]) ? 1.f : 0.f;
    const float skD  = dpp_shl1_zero(skf);       // allow_skip into 2i+3
    const float skD2 = dpp_shl1_zero(skD);       // allow_skip into 2i+5

    // unit init at t = 511
    float g0 = (lane == Sl) ? 1.f : 0.f;                 // l = 2*Sl (Sl<=63)
    float g1 = (Sl > 0 && lane == Sl - 1) ? 1.f : 0.f;   // l = 2*Sl-1
    float gX = (Sl >= S && lane == 63) ? 1.f : 0.f;      // l = 128 (Sl==64)
    int SHb = 0, kB = 0;
    float gsb = fmaxf(fmaxf(g0, g1), gX);

    asm volatile("s_waitcnt vmcnt(0)" ::: "memory");
    __builtin_amdgcn_sched_barrier(0);

#define LDSP(B, D) (&ldsB[wid][B][D][0])
#define ISSUEB(cc) do {                                                       \
    const float* cp_ = bp + (size_t)(496 - 16 * (cc)) * ROWF;                 \
    if (lane < 17) {                                                          \
        _Pragma("unroll")                                                     \
        for (int d_ = 0; d_ < CT; ++d_)                                       \
            __builtin_amdgcn_global_load_lds(cp_ + (size_t)d_ * ROWF + lane * 4, \
                                             &ldsB[wid][(cc) & 1][d_][0], 16, 0, 0); \
    } } while (0)

    ISSUEB(0); ISSUEB(1);
    for (int c = 0; c < NCBP; ++c) {             // rows 511..256 descending
        if (c < NCBP - 1) { asm volatile("s_waitcnt vmcnt(16)" ::: "memory"); }
        else              { asm volatile("s_waitcnt vmcnt(0)"  ::: "memory"); }
        __builtin_amdgcn_sched_barrier(0);
        int buf = c & 1;
        BWINC_BODY(LDSP, buf, 8);                // rows 15..8 of chunk
        BWINC_BODY(LDSP, buf, 0);                // rows 7..0
        if (c + 2 < NCBP) {
            __builtin_amdgcn_sched_barrier(0);
            ISSUEB(c + 2);
        }
    }

    // publish gamma_255 state (pending kB intentionally dropped; SHb = applied)
    float* st = gst + n * 136;
    float2 gv; gv.x = g0; gv.y = g1;
    *reinterpret_cast<float2*>(&st[2 * lane]) = gv;
    if (lane == 63) { st[128] = gX; st[129] = (float)SHb; }
#undef ISSUEB
#undef LDSP
}

// ---------------- final kernel: fwd(0..127) || bwd(255..128) + join@127 -----
__global__ __launch_bounds__(128) void k_final(
    const float* __restrict__ pp, const float* __restrict__ ee,
    float* __restrict__ gst, const int* __restrict__ labels,
    const int* __restrict__ in_len, const int* __restrict__ lab_len,
    float* __restrict__ out)
{
    __shared__ __align__(16) float ldsF[2][CT][ROWF];
    __shared__ __align__(16) float ldsT[2][CT][ROWF];
    __shared__ float gj[132];
    const int n = blockIdx.x;
    const int wid = threadIdx.x >> 6, lane = threadIdx.x & 63;
    const int Tin = in_len[n], Sl = lab_len[n];
    const float* bp = pp + (size_t)n * T * ROWF;
    const bool hot = (Tin == T);

    const int li   = labels[n * S + lane];
    const int lim1 = lane ? labels[n * S + lane - 1] : -1;
    const float skf  = (lane > 0 && li != 0 && li != lim1) ? 1.f : 0.f;
    const float skUf = dpp_shr1_zero(skf);
    const float skk  = skf * skUf;
    const float skD  = dpp_shl1_zero(skf);
    const float skD2 = dpp_shl1_zero(skD);

    float a0 = 0.f, a1 = 0.f, aX = 0.f;
    int SH = 0;

#define ISSUE_F(cc) do {                                                      \
    const float* cp_ = bp + (size_t)(cc) * CT * ROWF;                         \
    if (lane < 17) {                                                          \
        _Pragma("unroll")                                                     \
        for (int d_ = 0; d_ < CT; ++d_)                                       \
            __builtin_amdgcn_global_load_lds(cp_ + (size_t)d_ * ROWF + lane * 4, \
                                             &ldsF[(cc) & 1][d_][0], 16, 0, 0); \
    } } while (0)
#define ISSUE_T(cc) do {                                                      \
    const float* cp_ = bp + (size_t)(240 - 16 * (cc)) * ROWF;                 \
    if (lane < 17) {                                                          \
        _Pragma("unroll")                                                     \
        for (int d_ = 0; d_ < CT; ++d_)                                       \
            __builtin_amdgcn_global_load_lds(cp_ + (size_t)d_ * ROWF + lane * 4, \
                                             &ldsT[(cc) & 1][d_][0], 16, 0, 0); \
    } } while (0)

// ---- forward pair step (R11 verbatim) ----
#define PAIRS(B, D) do {                                                      \
    const float* R0_ = &ldsF[B][D][0];                                        \
    const float* R1_ = &ldsF[B][(D) + 1][0];                                  \
    float cb1 = R0_[0], cl1 = R0_[1 + lane];                                  \
    float cb2 = R1_[0], cl2 = R1_[1 + lane];                                  \
    float clU = dpp_shr1_zero(cl1);                                           \
    float W   = clU * cl2;                                                    \
    float A   = cb1 * cb2;                                                    \
    float B_  = clU * cb2;                                                    \
    float Cc  = A + B_;                                                       \
    float D_  = skUf * B_;                                                    \
    float s1  = cb1 + cl1;                                                    \
    float E   = s1 * cl2;                                                     \
    float F   = cl1 * cl2;                                                    \
    float G   = skf * W;                                                      \
    float H   = fmaf(skf, F + W, cb1 * cl2);                                  \
    float I   = skk * W;                                                      \
    float Y0  = cl1 * cb2;                                                    \
    float Y1  = s1 * cb2;                                                     \
    float Y2  = skf * Y0;                                                     \
    float p1  = dpp_shr1_zero(a1);                                            \
    float p0  = dpp_shr1_zero(a0);                                            \
    float p2  = dpp_shr1_zero(p1);                                            \
    float n0  = fmaf(p0, B_, a0 * A) + fmaf(p2, D_, p1 * Cc);                 \
    float n1  = fmaf(a1, F, a0 * E) + fmaf(p2, I, fmaf(p1, H, p0 * G));       \
    float nX  = fmaf(a1, Y1, aX * A) + fmaf(p1, Y2, a0 * Y0);                 \
    a0 = n0; a1 = n1; aX = nX;                                                \
} while (0)

#define WINDOW4(B, D0) do {                                                   \
    a0 = ldexpf(a0, kA); a1 = ldexpf(a1, kA); aX = ldexpf(aX, kA);            \
    SH += kA;                                                                 \
    float gnow_ = fmaxf(fmaxf(a0, a1), aX);                                   \
    PAIRS(B, D0);                                                             \
    gs = dpp_max_step<0xB1>(gs);  gs = dpp_max_step<0x4E>(gs);                \
    PAIRS(B, (D0) + 2);                                                       \
    gs = dpp_max_step<0x141>(gs); gs = dpp_max_step<0x140>(gs);               \
    PAIRS(B, (D0) + 4);                                                       \
    gs = dpp_max_step<0x142>(gs); gs = dpp_max_step<0x143>(gs);               \
    PAIRS(B, (D0) + 6);                                                       \
    {   unsigned b_ = (unsigned)__builtin_amdgcn_readlane(__float_as_int(gs), 63); \
        int e_ = (int)(b_ >> 23) - 127;                                       \
        kA = (b_ == 0u) ? 0 : (105 - e_ - kA);                                \
    }                                                                         \
    gs = gnow_;                                                               \
} while (0)

#define LDST(B, D) (&ldsT[B][D][0])

    asm volatile("s_waitcnt vmcnt(0)" ::: "memory");
    __builtin_amdgcn_sched_barrier(0);

    if (wid == 0) {
        if (hot) {
            // forward t = 0..127 (8 chunks)
            int kA = 0; float gs = 0.f;
            ISSUE_F(0); ISSUE_F(1);
            asm volatile("s_waitcnt vmcnt(16)" ::: "memory");
            __builtin_amdgcn_sched_barrier(0);
            a0 = (lane == 0) ? ldsF[0][0][0] : 0.f;
            a1 = (lane == 0 && Sl > 0) ? ldsF[0][0][1] : 0.f;
            {   // t = 1 single step
                float cb = ldsF[0][1][0], cl = ldsF[0][1][1 + lane];
                float p1 = dpp_shr1_zero(a1);
                float n0 = (a0 + p1) * cb;
                float n1 = fmaf(skf, p1, a0 + a1) * cl;
                float nX = (aX + a1) * cb;
                a0 = n0; a1 = n1; aX = nX;
            }
            PAIRS(0, 2); PAIRS(0, 4); PAIRS(0, 6);       // t = 2..7
            {   float g = wave_max_bcast(fmaxf(fmaxf(a0, a1), aX));
                unsigned b = __float_as_uint(g);
                int k0 = (b == 0u) ? 0 : (105 - ((int)(b >> 23) - 127));
                a0 = ldexpf(a0, k0); a1 = ldexpf(a1, k0); aX = ldexpf(aX, k0);
                SH += k0; kA = 0;
                gs = fmaxf(fmaxf(a0, a1), aX);
            }
            WINDOW4(0, 8);                               // t = 8..15
            __builtin_amdgcn_sched_barrier(0);
            ISSUE_F(2);
            for (int c = 1; c < NCF; ++c) {
                if (c < NCF - 1) { asm volatile("s_waitcnt vmcnt(16)" ::: "memory"); }
                else             { asm volatile("s_waitcnt vmcnt(0)"  ::: "memory"); }
                __builtin_amdgcn_sched_barrier(0);
                int buf = c & 1;
                WINDOW4(buf, 0);
                WINDOW4(buf, 8);
                if (c + 2 < NCF) {
                    __builtin_amdgcn_sched_barrier(0);
                    ISSUE_F(c + 2);
                }
            }
        } else {
            // generic fallback: full T per-step (R11-proven structure)
#define GSTEP(cc, dd) do {                                                    \
    float cb_ = ldsF[(cc) & 1][dd][0];                                        \
    float cl_ = ldsF[(cc) & 1][dd][1 + lane];                                 \
    float p1_ = dpp_shr1_zero(a1);                                            \
    float na0_ = (a0 + p1_) * cb_;                                            \
    float na1_ = fmaf(skf, p1_, a0 + a1) * cl_;                               \
    float naX_ = (aX + a1) * cb_;                                             \
    int t_ = (cc) * CT + (dd);                                                \
    bool act_ = (unsigned)(t_ - 1) < (unsigned)(Tin - 1);                     \
    a0 = act_ ? na0_ : a0;                                                    \
    a1 = act_ ? na1_ : a1;                                                    \
    aX = act_ ? naX_ : aX;                                                    \
    if (((dd) & 3) == 3) {                                                    \
        float g_ = wave_max_bcast(fmaxf(a0, fmaxf(a1, aX)));                  \
        unsigned b_ = __float_as_uint(g_);                                    \
        int k_ = (b_ == 0u) ? 0 : (100 - ((int)(b_ >> 23) - 127));            \
        a0 = ldexpf(a0, k_); a1 = ldexpf(a1, k_); aX = ldexpf(aX, k_);        \
        SH += k_;                                                             \
    }                                                                         \
} while (0)
            ISSUE_F(0); ISSUE_F(1);
            asm volatile("s_waitcnt vmcnt(16)" ::: "memory");
            __builtin_amdgcn_sched_barrier(0);
            a0 = (lane == 0) ? ldsF[0][0][0] : 0.f;
            a1 = (lane == 0 && Sl > 0) ? ldsF[0][0][1] : 0.f;
            #pragma unroll
            for (int d = 1; d < CT; ++d) GSTEP(0, d);
            __builtin_amdgcn_sched_barrier(0);
            ISSUE_F(2);
            for (int c = 1; c < NCG; ++c) {
                if (c < NCG - 1) { asm volatile("s_waitcnt vmcnt(16)" ::: "memory"); }
                else             { asm volatile("s_waitcnt vmcnt(0)"  ::: "memory"); }
                __builtin_amdgcn_sched_barrier(0);
                #pragma unroll
                for (int d = 0; d < CT; ++d) GSTEP(c, d);
                if (c + 2 < NCG) {
                    __builtin_amdgcn_sched_barrier(0);
                    ISSUE_F(c + 2);
                }
            }
#undef GSTEP
        }
    } else if (hot) {
        // backward tail: rows 255..128 (8 chunks, CPAIR), then publish gamma_127
        float* st = gst + n * 136;
        float2 g = *reinterpret_cast<const float2*>(&st[2 * lane]);
        float g0 = g.x, g1 = g.y;
        float gX = (lane == 63) ? st[128] : 0.f;
        int SHb = (int)st[129], kB = 0;
        float gsb = fmaxf(fmaxf(g0, g1), gX);

        ISSUE_T(0); ISSUE_T(1);
        for (int c = 0; c < NCBT; ++c) {
            if (c < NCBT - 1) { asm volatile("s_waitcnt vmcnt(16)" ::: "memory"); }
            else              { asm volatile("s_waitcnt vmcnt(0)"  ::: "memory"); }
            __builtin_amdgcn_sched_barrier(0);
            int buf = c & 1;
            BWINC_BODY(LDST, buf, 8);                    // rows 15..8
            BWINC_BODY(LDST, buf, 0);                    // rows 7..0
            if (c + 2 < NCBT) {
                __builtin_amdgcn_sched_barrier(0);
                ISSUE_T(c + 2);
            }
        }
        gj[2 * lane]     = g0;                           // UNSHIFTED (fp64 join)
        gj[2 * lane + 1] = g1;
        if (lane == 63) { gj[128] = gX; gj[130] = (float)SHb; }
    }

    __syncthreads();
    if (wid != 0) return;

    // ---------------- epilogue (wave 0) ----------------
    float se = 0.f;
    #pragma unroll
    for (int j = 0; j < 8; ++j) {
        int idx = lane + 64 * j;
        float ev = ee[n * T + idx];
        se += (idx < Tin) ? ev : 0.f;
    }
    for (int off = 32; off; off >>= 1) se += __shfl_xor(se, off);

    if (hot) {
        // P = sum_l alpha_127[l] * gamma_127[l]  (fp64)
        double term = (double)a0 * (double)gj[2 * lane]
                    + (double)a1 * (double)gj[2 * lane + 1];
        if (lane == 63) term += (double)aX * (double)gj[128];
        for (int off = 32; off; off >>= 1) term += __shfl_xor(term, off);
        if (lane == 0) {
            double SHb = (double)gj[130];
            double ll2 = log2(term) - (double)SH - SHb + (double)se;
            float loss = (float)(-ll2 * (double)LN2);
            if (!(loss < 5e29f)) loss = 0.f;             // zero_infinity (+NaN)
            atomicAdd(out, loss);
        }
    } else {
        float a_last = (Sl >= S) ? __shfl(aX, 63) : __shfl(a0, Sl);
        float a_prev_raw = __shfl(a1, (Sl > 0) ? (Sl - 1) : 0);
        float a_prev = (Sl > 0) ? a_prev_raw : 0.f;
        if (lane == 0) {
            float sum  = a_last + a_prev;
            float ll2  = log2f(sum) - (float)SH + se;
            float loss = -ll2 * LN2;
            if (!(loss < 5e29f)) loss = 0.f;
            atomicAdd(out, loss);
        }
    }
#undef LDST
#undef WINDOW4
#undef PAIRS
#undef ISSUE_F
#undef ISSUE_T
}

extern "C" void kernel_launch(void* const* d_in, const int* in_sizes, int n_in,
                              void* d_out, int out_size, void* d_ws, size_t ws_size,
                              hipStream_t stream) {
    const float* x       = (const float*)d_in[0];
    const int*   labels  = (const int*)d_in[1];
    const int*   in_len  = (const int*)d_in[2];
    const int*   lab_len = (const int*)d_in[3];
    float* out  = (float*)d_out;
    float* pp   = (float*)d_ws;                          // TN*ROWF floats
    float* ee   = pp + (size_t)TN * ROWF + 256;          // TN floats
    float* gst  = ee + TN + 32;                          // N*136 floats

    const int NB = 8 + HROWS / 4;                        // 2056 blocks
    // A: k1 for t in [256,512); block 0 zeroes out[0] (replaces memset)
    k_phase<<<NB, 256, 0, stream>>>(x, labels, pp, ee, gst, in_len, lab_len,
                                    out, HROWS, 0);
    // B: k1 for t in [0,256) + hidden bwd rows 511..256 (CPAIR)
    k_phase<<<NB, 256, 0, stream>>>(x, labels, pp, ee, gst, in_len, lab_len,
                                    out, 0, 1);
    // E: fwd(0..127) || bwd(255..128) + join@127 (fp64) + atomic sum
    k_final<<<N, 128, 0, stream>>>(pp, ee, gst, labels, in_len, lab_len, out);
}